// Round 4
// baseline (1536.880 us; speedup 1.0000x reference)
//
#include <hip/hip_runtime.h>

#define HID 256
#define NB 1024
#define NACT 16

typedef __bf16 bf16x8 __attribute__((ext_vector_type(8)));
typedef float  f32x4  __attribute__((ext_vector_type(4)));

// LDS byte offsets
#define HA_LO 32768
#define BBUF_OFF 65536      // 2 x 32768 double-buffered weight tiles
#define S_OFF   131072
#define T_OFF   132096
#define DP_OFF  133120      // 8 KB decoder partials
#define LDS_TOT 141312

__device__ __forceinline__ void gload_lds16(const void* g, void* l) {
    __builtin_amdgcn_global_load_lds(
        (const __attribute__((address_space(1))) void*)g,
        (__attribute__((address_space(3))) void*)l, 16, 0, 0);
}
__device__ __forceinline__ unsigned short f2bf(float x) {
    union { float f; unsigned u; } v; v.f = x;
    unsigned r = v.u + 0x7fff + ((v.u >> 16) & 1);
    return (unsigned short)(r >> 16);
}
__device__ __forceinline__ float bf2f(unsigned short b) {
    union { float f; unsigned u; } v; v.u = ((unsigned)b) << 16;
    return v.f;
}

// ---- prep: WA[256][1536] = [W1h0 stack | Aw stack]; WB[256][768] = W2 stack;
//            WD padded [16][776] = Wd stack; Wc f32 [256][256] = inv*W1c ----
#define NWA (256*1536)
#define NWB (256*768)
#define NWDP 16384          // padded to 32768 B
#define NWC (256*256)
__global__ __launch_bounds__(256) void prep_k(const float* __restrict__ W1,
                                              const float* __restrict__ W2,
                                              const float* __restrict__ Wd,
                                              unsigned short* __restrict__ WA,
                                              unsigned short* __restrict__ WB,
                                              unsigned short* __restrict__ WD,
                                              float* __restrict__ Wc) {
    int i = blockIdx.x * 256 + threadIdx.x;
    const float inv = 1.0f / 63.0f;
    if (i < NWA) {
        int n = i / 1536, k = i % 1536;
        float val; int r;
        if (k < 768) { r = k >> 8; int ks = k & 255; val = W1[(512 + ks) * HID + n]; }
        else { int kk = k - 768; r = kk >> 8; int ks = kk & 255;
               val = W1[ks * HID + n] - inv * W1[(256 + ks) * HID + n]; }
        unsigned short hi = f2bf(val);
        WA[i] = (r == 1) ? f2bf(val - bf2f(hi)) : hi;
    } else if (i < NWA + NWB) {
        int j = i - NWA;
        int n = j / 768, k = j % 768;
        int r = k >> 8, ks = k & 255;
        float val = W2[ks * HID + n];
        unsigned short hi = f2bf(val);
        WB[j] = (r == 1) ? f2bf(val - bf2f(hi)) : hi;
    } else if (i < NWA + NWB + NWDP) {
        int j = i - NWA - NWB;
        unsigned short o = 0;
        if (j < 16 * 776) {
            int n = j / 776, kp = j % 776;
            if (kp < 768) {
                int r = kp >> 8, ks = kp & 255;
                float val = Wd[ks * NACT + n];
                unsigned short hi = f2bf(val);
                o = (r == 1) ? f2bf(val - bf2f(hi)) : hi;
            }
        }
        WD[j] = o;
    } else {
        int j = i - NWA - NWB - NWDP;
        if (j < NWC) {
            int k = j >> 8, n = j & 255;
            Wc[j] = inv * W1[(256 + k) * HID + n];
        }
    }
}

// ---- double-buffered BK=64 K-loop: acc += A(hA swizzled) @ W-tile ----
template<int LD>
__device__ __forceinline__ void kloop(const unsigned short* __restrict__ W,
                                      int kstart, int nk,
                                      char* hA, char* Bb,
                                      f32x4 (&acc)[2][4],
                                      int tid, int wm, int wn, int l15, int g)
{
    // stage first tile into buf0
    #pragma unroll
    for (int p = 0; p < 4; ++p) {
        int c = p * 512 + tid;
        int n = c >> 3, s = c & 7;
        int sp = s ^ (n & 7);
        gload_lds16(W + (size_t)n * LD + kstart + sp * 8, Bb + c * 16);
    }
    int cur = 0;
    const int rxA = (l15 & 7) << 4;
    const int rowb0 = (wm * 32 + l15) * 512;
    const int rowb1 = (wm * 32 + 16 + l15) * 512;
    for (int t = 0; t < nk; ++t) {
        __syncthreads();                       // drains vmcnt: buf[cur] ready
        if (t + 1 < nk) {                      // issue-early stage of next tile
            int kk = kstart + (t + 1) * 64;
            char* dst = Bb + (cur ^ 1) * 32768;
            #pragma unroll
            for (int p = 0; p < 4; ++p) {
                int c = p * 512 + tid;
                int n = c >> 3, s = c & 7;
                int sp = s ^ (n & 7);
                gload_lds16(W + (size_t)n * LD + kk + sp * 8, dst + c * 16);
            }
        }
        const int k0 = kstart + t * 64;
        const char* bbase = Bb + cur * 32768;
        #pragma unroll
        for (int kh = 0; kh < 2; ++kh) {
            int kq = k0 + kh * 32;
            int reg = (kq >> 8) % 3;
            int aoff = (reg == 2) ? HA_LO : 0;
            int cb = (((kq & 255) * 2) + g * 16) ^ rxA;
            bf16x8 a0 = *(const bf16x8*)(hA + aoff + rowb0 + cb);
            bf16x8 a1 = *(const bf16x8*)(hA + aoff + rowb1 + cb);
            #pragma unroll
            for (int nt = 0; nt < 4; ++nt) {
                int n = wn * 64 + nt * 16 + l15;
                int off = n * 128 + (((kh * 64) | (g * 16)) ^ ((n & 7) << 4));
                bf16x8 bv = *(const bf16x8*)(bbase + off);
                acc[0][nt] = __builtin_amdgcn_mfma_f32_16x16x32_bf16(a0, bv, acc[0][nt], 0, 0, 0);
                acc[1][nt] = __builtin_amdgcn_mfma_f32_16x16x32_bf16(a1, bv, acc[1][nt], 0, 0, 0);
            }
        }
        cur ^= 1;
    }
}

// ---- the whole network for one batch per block ----
__global__ __launch_bounds__(512, 2) void fused_all(
    const int* __restrict__ ids, const float* __restrict__ emb,
    const unsigned short* __restrict__ WA, const unsigned short* __restrict__ WB,
    const unsigned short* __restrict__ WD, const float* __restrict__ Wc,
    const float* __restrict__ b1, const float* __restrict__ b2,
    const float* __restrict__ bd, float* __restrict__ out)
{
    __shared__ __align__(16) char lds[LDS_TOT];
    const int tid = threadIdx.x;
    const int lane = tid & 63;
    const int w = tid >> 6;
    const int wm = w >> 2, wn = w & 3;
    const int l15 = lane & 15, g = lane >> 4;
    const size_t rowbase = (size_t)blockIdx.x * 64;
    char* hA = lds;
    char* Bb = lds + BBUF_OFF;
    float* S  = (float*)(lds + S_OFF);
    float* Tl = (float*)(lds + T_OFF);
    float* Dp = (float*)(lds + DP_OFF);

    // ---- stage h0 = emb[ids] -> split hi/lo, XOR-swizzled ----
    {
        int r = tid >> 3, c0 = (tid & 7) * 32;
        int rx = (r & 7) << 4;
        const float4* src = (const float4*)(emb + (size_t)ids[rowbase + r] * HID + c0);
        char* dh = hA + r * 512;
        #pragma unroll
        for (int j = 0; j < 8; ++j) {
            float4 v = src[j];
            unsigned short h0 = f2bf(v.x), h1 = f2bf(v.y), h2 = f2bf(v.z), h3 = f2bf(v.w);
            unsigned short q0 = f2bf(v.x - bf2f(h0)), q1 = f2bf(v.y - bf2f(h1)),
                           q2 = f2bf(v.z - bf2f(h2)), q3 = f2bf(v.w - bf2f(h3));
            int byte = ((c0 + j * 4) * 2) ^ rx;
            *(uint2*)(dh + byte) = make_uint2((unsigned)h0 | ((unsigned)h1 << 16),
                                             (unsigned)h2 | ((unsigned)h3 << 16));
            *(uint2*)(dh + HA_LO + byte) = make_uint2((unsigned)q0 | ((unsigned)q1 << 16),
                                                      (unsigned)q2 | ((unsigned)q3 << 16));
        }
    }

    // ---- S/T helper (leading barriers make it callable right after writes) ----
    auto ST = [&]() {
        __syncthreads();
        if (tid < 256) {
            float s = 0.f;
            #pragma unroll 16
            for (int r = 0; r < 64; ++r) {
                int byte = r * 512 + ((tid * 2) ^ ((r & 7) << 4));
                s += bf2f(*(const unsigned short*)(hA + byte))
                   + bf2f(*(const unsigned short*)(hA + HA_LO + byte));
            }
            S[tid] = s;
        }
        __syncthreads();
        if (tid < 256) {
            float a = 0.f;
            #pragma unroll 8
            for (int k = 0; k < 256; ++k) a += S[k] * Wc[(k << 8) + tid];
            Tl[tid] = a;
        }
        // kloop's t=0 barrier publishes Tl before any consumer
    };
    ST();   // T for step 0 (leading barrier also covers h0 staging)

    f32x4 acc[2][4];
    f32x4 u0r[2][4];
    #pragma unroll
    for (int mt = 0; mt < 2; ++mt)
        #pragma unroll
        for (int nt = 0; nt < 4; ++nt) acc[mt][nt] = (f32x4){0.f, 0.f, 0.f, 0.f};

    for (int s = 0; s < 4; ++s) {
        // ---- phase A ----
        if (s == 0) {
            kloop<1536>(WA, 0, 12, hA, Bb, acc, tid, wm, wn, l15, g);   // h0 @ W1h0 stack
            #pragma unroll
            for (int nt = 0; nt < 4; ++nt) {
                float bb = b1[wn * 64 + nt * 16 + l15];
                #pragma unroll
                for (int mt = 0; mt < 2; ++mt)
                    #pragma unroll
                    for (int q = 0; q < 4; ++q) {
                        u0r[mt][nt][q] = acc[mt][nt][q] + bb;
                        acc[mt][nt][q] = 0.f;
                    }
            }
            kloop<1536>(WA, 768, 12, hA, Bb, acc, tid, wm, wn, l15, g); // h @ Aw stack
        } else {
            kloop<1536>(WA, 768, 12, hA, Bb, acc, tid, wm, wn, l15, g);
        }

        // ---- epilogue A: act = relu(acc + T + u0) -> hA (split) ----
        {
            float tv[4];
            #pragma unroll
            for (int nt = 0; nt < 4; ++nt) tv[nt] = Tl[wn * 64 + nt * 16 + l15];
            float hres[2][4][4];
            #pragma unroll
            for (int mt = 0; mt < 2; ++mt)
                #pragma unroll
                for (int nt = 0; nt < 4; ++nt)
                    #pragma unroll
                    for (int q = 0; q < 4; ++q) {
                        int row = wm * 32 + mt * 16 + g * 4 + q;
                        int col = wn * 64 + nt * 16 + l15;
                        int byte = row * 512 + ((col * 2) ^ ((row & 7) << 4));
                        hres[mt][nt][q] = bf2f(*(const unsigned short*)(hA + byte))
                                        + bf2f(*(const unsigned short*)(hA + HA_LO + byte));
                    }
            __syncthreads();   // all phase-A hA reads done before overwrite
            #pragma unroll
            for (int mt = 0; mt < 2; ++mt)
                #pragma unroll
                for (int nt = 0; nt < 4; ++nt)
                    #pragma unroll
                    for (int q = 0; q < 4; ++q) {
                        int row = wm * 32 + mt * 16 + g * 4 + q;
                        int col = wn * 64 + nt * 16 + l15;
                        int byte = row * 512 + ((col * 2) ^ ((row & 7) << 4));
                        float a = fmaxf(acc[mt][nt][q] + tv[nt] + u0r[mt][nt][q], 0.f);
                        unsigned short hi = f2bf(a);
                        *(unsigned short*)(hA + byte) = hi;
                        *(unsigned short*)(hA + HA_LO + byte) = f2bf(a - bf2f(hi));
                        acc[mt][nt][q] = 0.f;
                    }
            __syncthreads();   // act visible

            // ---- phase B: acc = act @ W2 stack ----
            kloop<768>(WB, 0, 12, hA, Bb, acc, tid, wm, wn, l15, g);

            // ---- epilogue B: hnew = hres + acc + b2 -> hA (split) ----
            float b2v[4];
            #pragma unroll
            for (int nt = 0; nt < 4; ++nt) b2v[nt] = b2[wn * 64 + nt * 16 + l15];
            __syncthreads();   // all phase-B hA(act)+Bbuf reads done
            #pragma unroll
            for (int mt = 0; mt < 2; ++mt)
                #pragma unroll
                for (int nt = 0; nt < 4; ++nt)
                    #pragma unroll
                    for (int q = 0; q < 4; ++q) {
                        int row = wm * 32 + mt * 16 + g * 4 + q;
                        int col = wn * 64 + nt * 16 + l15;
                        int byte = row * 512 + ((col * 2) ^ ((row & 7) << 4));
                        float hv = hres[mt][nt][q] + acc[mt][nt][q] + b2v[nt];
                        unsigned short hi = f2bf(hv);
                        *(unsigned short*)(hA + byte) = hi;
                        *(unsigned short*)(hA + HA_LO + byte) = f2bf(hv - bf2f(hi));
                        acc[mt][nt][q] = 0.f;
                    }
        }
        if (s < 3) ST();   // T for next step (leading barrier covers hnew writes)
    }

    // ---- decoder: logits = h @ Wd + bd (split-bf16 MFMA, k-split across waves) ----
    __syncthreads();                       // hnew written; Bbuf free
    #pragma unroll
    for (int p = 0; p < 4; ++p) {          // stage padded WD (32 KB flat copy)
        int c = p * 512 + tid;
        gload_lds16(WD + (size_t)c * 8, Bb + c * 16);
    }
    __syncthreads();
    {
        const int rxA = (l15 & 7) << 4;
        const int rf = w & 3, kh2 = w >> 2;
        const int rowd = (rf * 16 + l15) * 512;
        f32x4 dacc = (f32x4){0.f, 0.f, 0.f, 0.f};
        #pragma unroll
        for (int t = 0; t < 12; ++t) {
            int kq = kh2 * 384 + t * 32;
            int reg = kq >> 8;
            int aoff = (reg == 2) ? HA_LO : 0;
            int cb = (((kq & 255) * 2) + g * 16) ^ rxA;
            bf16x8 a = *(const bf16x8*)(hA + aoff + rowd + cb);
            bf16x8 bv = *(const bf16x8*)(Bb + l15 * 1552 + (kq + g * 8) * 2);
            dacc = __builtin_amdgcn_mfma_f32_16x16x32_bf16(a, bv, dacc, 0, 0, 0);
        }
        #pragma unroll
        for (int q = 0; q < 4; ++q)
            Dp[kh2 * 1024 + (rf * 16 + g * 4 + q) * 16 + l15] = dacc[q];
    }
    __syncthreads();
    #pragma unroll
    for (int e = 0; e < 2; ++e) {
        int idx = e * 512 + tid;
        int r = idx >> 4, a = idx & 15;
        out[(rowbase + r) * NACT + a] = Dp[r * 16 + a] + Dp[1024 + r * 16 + a] + bd[a];
    }
}

extern "C" void kernel_launch(void* const* d_in, const int* in_sizes, int n_in,
                              void* d_out, int out_size, void* d_ws, size_t ws_size,
                              hipStream_t stream) {
    const int*   ids = (const int*)d_in[0];
    const float* emb = (const float*)d_in[1];
    const float* W1  = (const float*)d_in[2];
    const float* b1  = (const float*)d_in[3];
    const float* W2  = (const float*)d_in[4];
    const float* b2  = (const float*)d_in[5];
    const float* Wd  = (const float*)d_in[6];
    const float* bd  = (const float*)d_in[7];
    float* out = (float*)d_out;

    char* p = (char*)d_ws;
    unsigned short* WA = (unsigned short*)p; p += (size_t)NWA * 2;    // 768 KB
    unsigned short* WB = (unsigned short*)p; p += (size_t)NWB * 2;    // 384 KB
    unsigned short* WD = (unsigned short*)p; p += (size_t)NWDP * 2;   // 32 KB padded
    float* Wc = (float*)p;                                            // 256 KB

    prep_k<<<(NWA + NWB + NWDP + NWC + 255) / 256, 256, 0, stream>>>(W1, W2, Wd, WA, WB, WD, Wc);
    fused_all<<<NB, 512, 0, stream>>>(ids, emb, WA, WB, WD, Wc, b1, b2, bd, out);
}

// Round 5
// 1484.426 us; speedup vs baseline: 1.0353x; 1.0353x over previous
//
#include <hip/hip_runtime.h>

#define HID 256
#define NB 1024
#define NACT 16

typedef __bf16 bf16x8 __attribute__((ext_vector_type(8)));
typedef float  f32x4  __attribute__((ext_vector_type(4)));

// LDS map (80 KB total -> 2 blocks/CU)
#define HA_LO  32768            // lo half of hA
#define WT_OFF 65536            // 16 KB weight tile (single buffer)
#define S_OFF  65536            // S overlays weight tile (1 KB)
#define T_OFF  (65536 + 4096)   // T overlays weight tile (1 KB)
#define DP_OFF 65536            // decoder partials overlay (8 KB)
#define LDS_TOT 81920

#define NWA (256*1536)
#define NWB (256*768)
#define NWD (16*768)
#define NWC (256*256)

__device__ __forceinline__ void gload_lds16(const void* g, void* l) {
    __builtin_amdgcn_global_load_lds(
        (const __attribute__((address_space(1))) void*)g,
        (__attribute__((address_space(3))) void*)l, 16, 0, 0);
}
__device__ __forceinline__ unsigned short f2bf(float x) {
    union { float f; unsigned u; } v; v.f = x;
    unsigned r = v.u + 0x7fff + ((v.u >> 16) & 1);
    return (unsigned short)(r >> 16);
}
__device__ __forceinline__ float bf2f(unsigned short b) {
    union { float f; unsigned u; } v; v.u = ((unsigned)b) << 16;
    return v.f;
}

// ---- prep: WA[256][1536]=[W1h0 stack|Aw stack]; WB[256][768]=W2 stack;
//            WD[16][768]=Wd stack; Wc f32 = inv*W1c ----
__global__ __launch_bounds__(256) void prep_k(const float* __restrict__ W1,
                                              const float* __restrict__ W2,
                                              const float* __restrict__ Wd,
                                              unsigned short* __restrict__ WA,
                                              unsigned short* __restrict__ WB,
                                              unsigned short* __restrict__ WD,
                                              float* __restrict__ Wc) {
    int i = blockIdx.x * 256 + threadIdx.x;
    const float inv = 1.0f / 63.0f;
    if (i < NWA) {
        int n = i / 1536, k = i % 1536;
        float val; int r;
        if (k < 768) { r = k >> 8; int ks = k & 255; val = W1[(512 + ks) * HID + n]; }
        else { int kk = k - 768; r = kk >> 8; int ks = kk & 255;
               val = W1[ks * HID + n] - inv * W1[(256 + ks) * HID + n]; }
        unsigned short hi = f2bf(val);
        WA[i] = (r == 1) ? f2bf(val - bf2f(hi)) : hi;
    } else if (i < NWA + NWB) {
        int j = i - NWA;
        int n = j / 768, k = j % 768;
        int r = k >> 8, ks = k & 255;
        float val = W2[ks * HID + n];
        unsigned short hi = f2bf(val);
        WB[j] = (r == 1) ? f2bf(val - bf2f(hi)) : hi;
    } else if (i < NWA + NWB + NWD) {
        int j = i - NWA - NWB;
        int n = j / 768, kp = j % 768;
        int r = kp >> 8, ks = kp & 255;
        float val = Wd[ks * NACT + n];
        unsigned short hi = f2bf(val);
        WD[j] = (r == 1) ? f2bf(val - bf2f(hi)) : hi;
    } else {
        int j = i - NWA - NWB - NWD;
        if (j < NWC) {
            int k = j >> 8, n = j & 255;
            Wc[j] = inv * W1[(256 + k) * HID + n];
        }
    }
}

// ---- BK=32 single-buffer K-loop (round-3-proven addressing) ----
// Caller must __syncthreads() BEFORE calling (protects Wt region) and AFTER
// (before anyone writes hA).
template<int LD>
__device__ __forceinline__ void kloop(const unsigned short* __restrict__ W,
                                      int kstart, char* hA, char* Wt,
                                      f32x4 (&acc)[2][4],
                                      int tid, int wm, int wn, int l15, int g)
{
    const int rxA = (l15 & 7) << 4;
    const int rowb0 = (wm * 32 + l15) * 512;
    const int rowb1 = rowb0 + 16 * 512;
    for (int t = 0; t < 24; ++t) {
        if (t) __syncthreads();
        const int k0 = kstart + t * 32;
        #pragma unroll
        for (int p = 0; p < 2; ++p) {
            int c = p * 512 + tid;
            int n = c >> 2, s = c & 3;
            int ss = s ^ ((n >> 1) & 3);
            gload_lds16(W + (size_t)n * LD + k0 + ss * 8, Wt + c * 16);
        }
        __syncthreads();
        const int reg = (k0 >> 8) % 3;
        const int aoff = (reg == 2) ? HA_LO : 0;
        const int cb = (((k0 & 255) * 2) + g * 16) ^ rxA;
        bf16x8 a0 = *(const bf16x8*)(hA + aoff + rowb0 + cb);
        bf16x8 a1 = *(const bf16x8*)(hA + aoff + rowb1 + cb);
        #pragma unroll
        for (int nt = 0; nt < 4; ++nt) {
            int n = wn * 64 + nt * 16 + l15;
            int off = n * 64 + ((g ^ ((n >> 1) & 3)) << 4);
            bf16x8 bv = *(const bf16x8*)(Wt + off);
            acc[0][nt] = __builtin_amdgcn_mfma_f32_16x16x32_bf16(a0, bv, acc[0][nt], 0, 0, 0);
            acc[1][nt] = __builtin_amdgcn_mfma_f32_16x16x32_bf16(a1, bv, acc[1][nt], 0, 0, 0);
        }
    }
}

// ---- whole network, one batch per block ----
__global__ __launch_bounds__(512, 4) void fused_all(
    const int* __restrict__ ids, const float* __restrict__ emb,
    const unsigned short* __restrict__ WA, const unsigned short* __restrict__ WB,
    const unsigned short* __restrict__ WD, const float* __restrict__ Wc,
    const float* __restrict__ b1, const float* __restrict__ b2,
    const float* __restrict__ bd, float* __restrict__ out)
{
    __shared__ __align__(16) char lds[LDS_TOT];
    const int tid = threadIdx.x;
    const int lane = tid & 63;
    const int w = tid >> 6;
    const int wm = w >> 2, wn = w & 3;
    const int l15 = lane & 15, g = lane >> 4;
    const size_t rowbase = (size_t)blockIdx.x * 64;
    char* hA = lds;
    char* Wt = lds + WT_OFF;
    float* S  = (float*)(lds + S_OFF);
    float* Tl = (float*)(lds + T_OFF);
    float* Dp = (float*)(lds + DP_OFF);

    // ---- stage h0 = emb[ids] -> split hi/lo, XOR-swizzled ----
    {
        int r = tid >> 3, c0 = (tid & 7) * 32;
        int rx = (r & 7) << 4;
        const float4* src = (const float4*)(emb + (size_t)ids[rowbase + r] * HID + c0);
        char* dh = hA + r * 512;
        #pragma unroll
        for (int j = 0; j < 8; ++j) {
            float4 v = src[j];
            unsigned short h0 = f2bf(v.x), h1 = f2bf(v.y), h2 = f2bf(v.z), h3 = f2bf(v.w);
            unsigned short q0 = f2bf(v.x - bf2f(h0)), q1 = f2bf(v.y - bf2f(h1)),
                           q2 = f2bf(v.z - bf2f(h2)), q3 = f2bf(v.w - bf2f(h3));
            int byte = ((c0 + j * 4) * 2) ^ rx;
            *(uint2*)(dh + byte) = make_uint2((unsigned)h0 | ((unsigned)h1 << 16),
                                             (unsigned)h2 | ((unsigned)h3 << 16));
            *(uint2*)(dh + HA_LO + byte) = make_uint2((unsigned)q0 | ((unsigned)q1 << 16),
                                                      (unsigned)q2 | ((unsigned)q3 << 16));
        }
    }

    // ---- S/T: T[col] = (sum_rows h) @ Wc, into overlay region ----
    auto ST = [&]() {
        __syncthreads();                 // h writes visible; Wt region free
        if (tid < 256) {
            float s = 0.f;
            #pragma unroll 16
            for (int r = 0; r < 64; ++r) {
                int byte = r * 512 + ((tid * 2) ^ ((r & 7) << 4));
                s += bf2f(*(const unsigned short*)(hA + byte))
                   + bf2f(*(const unsigned short*)(hA + HA_LO + byte));
            }
            S[tid] = s;
        }
        __syncthreads();
        if (tid < 256) {
            float a = 0.f;
            #pragma unroll 8
            for (int k = 0; k < 256; ++k) a += S[k] * Wc[(k << 8) + tid];
            Tl[tid] = a;
        }
        __syncthreads();                 // T visible for tv read
    };

    ST();
    float tv[4];
    #pragma unroll
    for (int nt = 0; nt < 4; ++nt) tv[nt] = Tl[wn * 64 + nt * 16 + l15];

    f32x4 acc[2][4], u0r[2][4];
    #pragma unroll
    for (int mt = 0; mt < 2; ++mt)
        #pragma unroll
        for (int nt = 0; nt < 4; ++nt) acc[mt][nt] = (f32x4){0.f, 0.f, 0.f, 0.f};

    for (int s = 0; s < 4; ++s) {
        // ---- phase A ----
        if (s == 0) {
            __syncthreads();                               // tv read done; Wt free
            kloop<1536>(WA, 0, hA, Wt, acc, tid, wm, wn, l15, g);   // h0 @ W1h0
            #pragma unroll
            for (int nt = 0; nt < 4; ++nt) {
                float bb = b1[wn * 64 + nt * 16 + l15];
                #pragma unroll
                for (int mt = 0; mt < 2; ++mt)
                    #pragma unroll
                    for (int q = 0; q < 4; ++q) {
                        u0r[mt][nt][q] = acc[mt][nt][q] + bb;
                        acc[mt][nt][q] = 0.f;
                    }
            }
        }
        __syncthreads();
        kloop<1536>(WA, 768, hA, Wt, acc, tid, wm, wn, l15, g);     // h @ Aw

        // ---- epilogue A: per-element RMW; acc becomes hres + b2 ----
        __syncthreads();                 // all phase-A hA/Wt reads done
        {
            #pragma unroll
            for (int mt = 0; mt < 2; ++mt)
                #pragma unroll
                for (int nt = 0; nt < 4; ++nt) {
                    float b2v = b2[wn * 64 + nt * 16 + l15];
                    #pragma unroll
                    for (int q = 0; q < 4; ++q) {
                        int row = wm * 32 + mt * 16 + g * 4 + q;
                        int col = wn * 64 + nt * 16 + l15;
                        int byte = row * 512 + ((col * 2) ^ ((row & 7) << 4));
                        float hres = bf2f(*(const unsigned short*)(hA + byte))
                                   + bf2f(*(const unsigned short*)(hA + HA_LO + byte));
                        float a = fmaxf(acc[mt][nt][q] + tv[nt] + u0r[mt][nt][q], 0.f);
                        unsigned short hi = f2bf(a);
                        *(unsigned short*)(hA + byte) = hi;
                        *(unsigned short*)(hA + HA_LO + byte) = f2bf(a - bf2f(hi));
                        acc[mt][nt][q] = hres + b2v;       // phase-B accumulator init
                    }
                }
        }
        __syncthreads();                 // act visible

        // ---- phase B: acc += act @ W2 ----
        kloop<768>(WB, 0, hA, Wt, acc, tid, wm, wn, l15, g);

        // ---- epilogue B: hnew = acc -> hA split ----
        __syncthreads();                 // all phase-B reads done
        #pragma unroll
        for (int mt = 0; mt < 2; ++mt)
            #pragma unroll
            for (int nt = 0; nt < 4; ++nt)
                #pragma unroll
                for (int q = 0; q < 4; ++q) {
                    int row = wm * 32 + mt * 16 + g * 4 + q;
                    int col = wn * 64 + nt * 16 + l15;
                    int byte = row * 512 + ((col * 2) ^ ((row & 7) << 4));
                    float hv = acc[mt][nt][q];
                    unsigned short hi = f2bf(hv);
                    *(unsigned short*)(hA + byte) = hi;
                    *(unsigned short*)(hA + HA_LO + byte) = f2bf(hv - bf2f(hi));
                    acc[mt][nt][q] = 0.f;
                }

        if (s < 3) {
            ST();                         // leading barrier covers hnew writes
            #pragma unroll
            for (int nt = 0; nt < 4; ++nt) tv[nt] = Tl[wn * 64 + nt * 16 + l15];
        }
    }

    // ---- decoder: logits = h @ Wd + bd (B-frags direct from global/L2) ----
    __syncthreads();                     // hnew visible; Wt region free for Dp
    {
        const int rxA = (l15 & 7) << 4;
        const int rf = w & 3, kh2 = w >> 2;
        const int rowd = (rf * 16 + l15) * 512;
        f32x4 dacc = (f32x4){0.f, 0.f, 0.f, 0.f};
        #pragma unroll
        for (int t = 0; t < 12; ++t) {
            int kq = kh2 * 384 + t * 32;
            int reg = (kq >> 8) % 3;
            int aoff = (reg == 2) ? HA_LO : 0;
            int cb = (((kq & 255) * 2) + g * 16) ^ rxA;
            bf16x8 a = *(const bf16x8*)(hA + aoff + rowd + cb);
            bf16x8 bv = *(const bf16x8*)(WD + (size_t)l15 * 768 + kq + g * 8);
            dacc = __builtin_amdgcn_mfma_f32_16x16x32_bf16(a, bv, dacc, 0, 0, 0);
        }
        #pragma unroll
        for (int q = 0; q < 4; ++q)
            Dp[kh2 * 1024 + (rf * 16 + g * 4 + q) * 16 + l15] = dacc[q];
    }
    __syncthreads();
    #pragma unroll
    for (int e = 0; e < 2; ++e) {
        int idx = e * 512 + tid;
        int r = idx >> 4, a = idx & 15;
        out[(rowbase + r) * NACT + a] = Dp[r * 16 + a] + Dp[1024 + r * 16 + a] + bd[a];
    }
}

extern "C" void kernel_launch(void* const* d_in, const int* in_sizes, int n_in,
                              void* d_out, int out_size, void* d_ws, size_t ws_size,
                              hipStream_t stream) {
    const int*   ids = (const int*)d_in[0];
    const float* emb = (const float*)d_in[1];
    const float* W1  = (const float*)d_in[2];
    const float* b1  = (const float*)d_in[3];
    const float* W2  = (const float*)d_in[4];
    const float* b2  = (const float*)d_in[5];
    const float* Wd  = (const float*)d_in[6];
    const float* bd  = (const float*)d_in[7];
    float* out = (float*)d_out;

    char* p = (char*)d_ws;
    unsigned short* WA = (unsigned short*)p; p += (size_t)NWA * 2;
    unsigned short* WB = (unsigned short*)p; p += (size_t)NWB * 2;
    unsigned short* WD = (unsigned short*)p; p += (size_t)NWD * 2;
    float* Wc = (float*)p;

    prep_k<<<(NWA + NWB + NWD + NWC + 255) / 256, 256, 0, stream>>>(W1, W2, Wd, WA, WB, WD, Wc);
    fused_all<<<NB, 512, 0, stream>>>(ids, emb, WA, WB, WD, Wc, b1, b2, bd, out);
}